// Round 5
// baseline (363.717 us; speedup 1.0000x reference)
//
#include <hip/hip_runtime.h>
#include <stdint.h>

// Problem shapes (fixed by setup_inputs)
#define BB 8
#define NN 4096
#define FF 2048
#define EE 128

typedef __attribute__((ext_vector_type(8))) short short8;
typedef __attribute__((ext_vector_type(4))) float floatx4;

__device__ __forceinline__ unsigned short f2bf(float x) {
    union { float f; uint32_t u; } v; v.f = x;
    uint32_t u = v.u;
    return (unsigned short)((u + 0x7FFFu + ((u >> 16) & 1u)) >> 16);
}

__device__ __forceinline__ float wred_sum(float v) {
#pragma unroll
    for (int o = 32; o; o >>= 1) v += __shfl_xor(v, o, 64);
    return v;
}

#define NFB (BB * FF / 4)   // 4096 blocks for fact prep (4 waves each)
#define NEB (BB * NN / 4)   // 8192 blocks for entity prep

// ---------------------------------------------------------------------------
// Fused prep. Fact branch: C_sp/C_po + fact2/fact3 as bf16 scaled by -2,
// stored MFMA-fragment-tiled: [b][ftile=f/16][kslot=k/8][row=f%16][8 bf16]
// so the main kernel's B-frag loads are wave-contiguous 1KB.
// Entity branch: ||ent||^2 + ent bf16 in the same tiled layout (unscaled).
// ---------------------------------------------------------------------------
__global__ __launch_bounds__(256) void prep_all(
    const float* __restrict__ rel, const float* __restrict__ arg1,
    const float* __restrict__ arg2, const float* __restrict__ f1,
    const float* __restrict__ f2, const float* __restrict__ f3,
    const float* __restrict__ ent, const int* __restrict__ nbf,
    char* __restrict__ f2t, char* __restrict__ f3t, char* __restrict__ entt,
    float* __restrict__ Csp, float* __restrict__ Cpo, float* __restrict__ enorm)
{
    int lane = threadIdx.x & 63;
    if (blockIdx.x < NFB) {
        int gid = blockIdx.x * 4 + (threadIdx.x >> 6);   // over B*F
        int b = gid >> 11;
        int f = gid & (FF - 1);

        const float2* rp  = (const float2*)(rel  + (size_t)b * EE);
        const float2* a1p = (const float2*)(arg1 + (size_t)b * EE);
        const float2* a2p = (const float2*)(arg2 + (size_t)b * EE);
        const float2* p1  = (const float2*)(f1 + (size_t)gid * EE);
        const float2* p2  = (const float2*)(f2 + (size_t)gid * EE);
        const float2* p3  = (const float2*)(f3 + (size_t)gid * EE);

        float2 vr = rp[lane], va1 = a1p[lane], va2 = a2p[lane];
        float2 v1 = p1[lane], v2 = p2[lane], v3 = p3[lane];

        float dx, dy;
        dx = vr.x - v1.x;  dy = vr.y - v1.y;  float dr  = dx*dx + dy*dy;
        dx = va1.x - v2.x; dy = va1.y - v2.y; float da1 = dx*dx + dy*dy;
        dx = va2.x - v3.x; dy = va2.y - v3.y; float da2 = dx*dx + dy*dy;
        float s2 = v2.x*v2.x + v2.y*v2.y;
        float s3 = v3.x*v3.x + v3.y*v3.y;

        // tiled store of -2*fact (exact pow2 scaling in bf16)
        // lane covers k = {2*lane, 2*lane+1}; kslot = lane>>2
        size_t base = ((size_t)b << 19) + (size_t)(f >> 4) * 4096 +
                      ((size_t)(lane >> 2) << 8) + ((f & 15) << 4) + ((lane & 3) << 2);
        uint32_t pk2 = (uint32_t)f2bf(-2.f * v2.x) | ((uint32_t)f2bf(-2.f * v2.y) << 16);
        uint32_t pk3 = (uint32_t)f2bf(-2.f * v3.x) | ((uint32_t)f2bf(-2.f * v3.y) << 16);
        *(uint32_t*)(f2t + base) = pk2;
        *(uint32_t*)(f3t + base) = pk3;

        dr = wred_sum(dr); da1 = wred_sum(da1); da2 = wred_sum(da2);
        s2 = wred_sum(s2); s3 = wred_sum(s3);

        if (lane == 0) {
            bool fv = f < nbf[b];
            Csp[gid] = fv ? (dr + da1 + s3) : 1e30f;
            Cpo[gid] = fv ? (dr + da2 + s2) : 1e30f;
        }
    } else {
        int gid = (blockIdx.x - NFB) * 4 + (threadIdx.x >> 6);   // over B*N
        int b = gid >> 12;
        int n = gid & (NN - 1);
        const float2* p = (const float2*)(ent + (size_t)gid * EE);
        float2 v = p[lane];
        size_t base = ((size_t)b << 20) + (size_t)(n >> 4) * 4096 +
                      ((size_t)(lane >> 2) << 8) + ((n & 15) << 4) + ((lane & 3) << 2);
        *(uint32_t*)(entt + base) =
            (uint32_t)f2bf(v.x) | ((uint32_t)f2bf(v.y) << 16);
        float nrm = wred_sum(v.x*v.x + v.y*v.y);
        if (lane == 0) enorm[gid] = nrm;
    }
}

// ---------------------------------------------------------------------------
// Main fused GEMM-min kernel. NO LDS, NO barriers.
// 4096 independent single-wave blocks: bid = b(3 bits, XCD affinity) |
// ng(64-row group) | fs(3 bits). Each wave: 64 entity rows x 256 facts x both
// tensors = 16 tiles. 16 waves/CU = 4 waves/SIMD at VGPR=128 (pinned by
// __launch_bounds__(64,4)) — latency hiding via occupancy; L2 traffic is
// invariant vs fewer/larger waves. B-frags stream from XCD-local L2 as
// wave-contiguous 1KB loads in MFMA layout; 2-deep register pipeline.
// Facts pre-scaled by -2, acc initialized from C via MFMA C-in, so the
// epilogue is min-only. Writes partial mins to pm.
// ---------------------------------------------------------------------------
__global__ __launch_bounds__(64, 4) void kb_main(
    const char* __restrict__ entt, const char* __restrict__ f3t,
    const char* __restrict__ f2t,
    const float* __restrict__ Csp, const float* __restrict__ Cpo,
    float* __restrict__ pm)
{
    int bid = blockIdx.x;
    int b  = bid & 7;
    int r  = bid >> 3;          // 0..511
    int fs = r >> 6;            // 0..7
    int ng = r & 63;            // 64-row entity group
    int lane = threadIdx.x & 63;
    int l15 = lane & 15, kgrp = lane >> 4;

    // A-frags: 64 entity rows (4 ntiles) x full K from tiled entt
    short8 a[4][4];
    {
        const char* ab = entt + ((size_t)b << 20) + ((size_t)ng << 14) + (l15 << 4);
#pragma unroll
        for (int i = 0; i < 4; ++i)
#pragma unroll
            for (int kk = 0; kk < 4; ++kk)
                a[i][kk] = *(const short8*)(ab + i * 4096 + ((kk * 4 + kgrp) << 8));
    }

    const char* p3 = f3t + ((size_t)b << 19) + (size_t)fs * (16 * 4096) +
                     (kgrp << 8) + (l15 << 4);
    const char* p2 = f2t + ((size_t)b << 19) + (size_t)fs * (16 * 4096) +
                     (kgrp << 8) + (l15 << 4);
    const float* c3 = Csp + b * FF + fs * 256 + l15;
    const float* c2 = Cpo + b * FF + fs * 256 + l15;

    float rm3[4][4], rm2[4][4];
#pragma unroll
    for (int i = 0; i < 4; ++i)
#pragma unroll
        for (int q = 0; q < 4; ++q) { rm3[i][q] = 3.0e38f; rm2[i][q] = 3.0e38f; }

    short8 bA3[4], bA2[4], bB3[4], bB2[4];

#define LOADB(d3, d2, ft) do {                                              \
    _Pragma("unroll") for (int kk = 0; kk < 4; ++kk) {                      \
        d3[kk] = *(const short8*)(p3 + (ft) * 4096 + kk * 1024);            \
        d2[kk] = *(const short8*)(p2 + (ft) * 4096 + kk * 1024);            \
    } } while (0)

#define STEP(s3v, s2v, ft) do {                                             \
    float cv3 = c3[(ft) * 16], cv2 = c2[(ft) * 16];                         \
    floatx4 acc3[4], acc2[4];                                               \
    _Pragma("unroll") for (int i = 0; i < 4; ++i) {                         \
        acc3[i] = floatx4{cv3, cv3, cv3, cv3};                              \
        acc2[i] = floatx4{cv2, cv2, cv2, cv2};                              \
    }                                                                       \
    _Pragma("unroll") for (int kk = 0; kk < 4; ++kk)                        \
        _Pragma("unroll") for (int i = 0; i < 4; ++i)                       \
            acc3[i] = __builtin_amdgcn_mfma_f32_16x16x32_bf16(              \
                a[i][kk], s3v[kk], acc3[i], 0, 0, 0);                       \
    _Pragma("unroll") for (int kk = 0; kk < 4; ++kk)                        \
        _Pragma("unroll") for (int i = 0; i < 4; ++i)                       \
            acc2[i] = __builtin_amdgcn_mfma_f32_16x16x32_bf16(              \
                a[i][kk], s2v[kk], acc2[i], 0, 0, 0);                       \
    _Pragma("unroll") for (int i = 0; i < 4; ++i)                           \
        _Pragma("unroll") for (int q = 0; q < 4; ++q) {                     \
            rm3[i][q] = fminf(rm3[i][q], acc3[i][q]);                       \
            rm2[i][q] = fminf(rm2[i][q], acc2[i][q]);                       \
        } } while (0)

    LOADB(bA3, bA2, 0);
    for (int ft = 0; ft < 16; ft += 2) {
        LOADB(bB3, bB2, ft + 1);            // prefetch odd tile
        STEP(bA3, bA2, ft);
        if (ft < 14) LOADB(bA3, bA2, ft + 2);   // prefetch next even tile
        STEP(bB3, bB2, ft + 1);
    }
#undef LOADB
#undef STEP

    // lane-group min-reduce, write partial min-distances
    float* q0 = pm + (((size_t)fs * 2 + 0) * BB + b) * NN + ng * 64;
    float* q1 = pm + (((size_t)fs * 2 + 1) * BB + b) * NN + ng * 64;
#pragma unroll
    for (int i = 0; i < 4; ++i)
#pragma unroll
        for (int q = 0; q < 4; ++q) {
            float vs = rm3[i][q], vp = rm2[i][q];
#pragma unroll
            for (int o = 1; o < 16; o <<= 1) {
                vs = fminf(vs, __shfl_xor(vs, o, 64));
                vp = fminf(vp, __shfl_xor(vp, o, 64));
            }
            if (l15 == 0) {
                int row = i * 16 + kgrp * 4 + q;
                q0[row] = vs;
                q1[row] = vp;
            }
        }
}

// ---------------------------------------------------------------------------
// Combine: min over the 8 F-split partials, add ||ent||^2, exp, entity mask.
// ---------------------------------------------------------------------------
__global__ __launch_bounds__(512) void combine(
    const float* __restrict__ pm, const float* __restrict__ enorm,
    const int* __restrict__ nbe, float* __restrict__ out)
{
    int idx = blockIdx.x * 512 + threadIdx.x;   // over 2*B*N
    int br  = idx >> 15;
    int rem = idx & 32767;
    int b   = rem >> 12;
    int n   = rem & 4095;
    float d = 3.0e38f;
#pragma unroll
    for (int fsp = 0; fsp < 8; ++fsp)
        d = fminf(d, pm[(((size_t)fsp * 2 + br) * BB + b) * NN + n]);
    bool valid = n < nbe[b];
    out[idx] = valid ? __expf(-0.5f * (d + enorm[(size_t)b * NN + n])) : 0.f;
}

// ---------------------------------------------------------------------------
// Workspace layout (bytes):
//   [0,      4MB)   fact2 bf16 * -2, MFMA-tiled
//   [4MB,    8MB)   fact3 bf16 * -2, MFMA-tiled
//   [8MB,   16MB)   ent bf16, MFMA-tiled
//   [16MB,        +64KB)   C_sp
//   [16MB+64K,    +64KB)   C_po
//   [16MB+128K,  +128KB)   ent_norm
//   [16MB+256K,    +2MB)   pm partial mins [fs*2+branch][B][N]
// ---------------------------------------------------------------------------
extern "C" void kernel_launch(void* const* d_in, const int* in_sizes, int n_in,
                              void* d_out, int out_size, void* d_ws, size_t ws_size,
                              hipStream_t stream) {
    const float* rel  = (const float*)d_in[0];
    const float* arg1 = (const float*)d_in[1];
    const float* arg2 = (const float*)d_in[2];
    const float* f1   = (const float*)d_in[3];
    const float* f2   = (const float*)d_in[4];
    const float* f3   = (const float*)d_in[5];
    const float* ent  = (const float*)d_in[6];
    const int*   nbf  = (const int*)d_in[7];
    const int*   nbe  = (const int*)d_in[8];

    char* ws = (char*)d_ws;
    char* f2t  = ws;
    char* f3t  = ws + (4u << 20);
    char* entt = ws + (8u << 20);
    float* Csp   = (float*)(ws + (16u << 20));
    float* Cpo   = (float*)(ws + (16u << 20) + 65536);
    float* enorm = (float*)(ws + (16u << 20) + 131072);
    float* pm    = (float*)(ws + (16u << 20) + 262144);
    float* out = (float*)d_out;

    hipLaunchKernelGGL(prep_all, dim3(NFB + NEB), dim3(256), 0, stream,
                       rel, arg1, arg2, f1, f2, f3, ent, nbf,
                       f2t, f3t, entt, Csp, Cpo, enorm);
    hipLaunchKernelGGL(kb_main, dim3(4096), dim3(64), 0, stream,
                       entt, f3t, f2t, Csp, Cpo, pm);
    hipLaunchKernelGGL(combine, dim3(128), dim3(512), 0, stream,
                       pm, enorm, nbe, out);
}

// Round 6
// 54.047 us; speedup vs baseline: 6.7296x; 6.7296x over previous
//
#include <hip/hip_runtime.h>
#include <stdint.h>

// Problem shapes (fixed by setup_inputs)
#define BB 8
#define NN 4096
#define FF 2048
#define EE 128

typedef __attribute__((ext_vector_type(8))) short short8;
typedef __attribute__((ext_vector_type(4))) float floatx4;

__device__ __forceinline__ unsigned short f2bf(float x) {
    union { float f; uint32_t u; } v; v.f = x;
    uint32_t u = v.u;
    return (unsigned short)((u + 0x7FFFu + ((u >> 16) & 1u)) >> 16);
}

__device__ __forceinline__ float wred_sum(float v) {
#pragma unroll
    for (int o = 32; o; o >>= 1) v += __shfl_xor(v, o, 64);
    return v;
}

#define NFB (BB * FF / 4)   // 4096 blocks for fact prep (4 waves each)
#define NEB (BB * NN / 4)   // 8192 blocks for entity prep

// ---------------------------------------------------------------------------
// Fused prep. Fact branch: C_sp/C_po + fact2/fact3 as bf16 scaled by -2,
// stored MFMA-fragment-tiled: [b][ftile=f/16][kslot=k/8][row=f%16][8 bf16]
// so the main kernel's B-frag loads are wave-contiguous 1KB.
// Entity branch: ||ent||^2 + ent bf16 in the same tiled layout (unscaled).
// ---------------------------------------------------------------------------
__global__ __launch_bounds__(256) void prep_all(
    const float* __restrict__ rel, const float* __restrict__ arg1,
    const float* __restrict__ arg2, const float* __restrict__ f1,
    const float* __restrict__ f2, const float* __restrict__ f3,
    const float* __restrict__ ent, const int* __restrict__ nbf,
    char* __restrict__ f2t, char* __restrict__ f3t, char* __restrict__ entt,
    float* __restrict__ Csp, float* __restrict__ Cpo, float* __restrict__ enorm)
{
    int lane = threadIdx.x & 63;
    if (blockIdx.x < NFB) {
        int gid = blockIdx.x * 4 + (threadIdx.x >> 6);   // over B*F
        int b = gid >> 11;
        int f = gid & (FF - 1);

        const float2* rp  = (const float2*)(rel  + (size_t)b * EE);
        const float2* a1p = (const float2*)(arg1 + (size_t)b * EE);
        const float2* a2p = (const float2*)(arg2 + (size_t)b * EE);
        const float2* p1  = (const float2*)(f1 + (size_t)gid * EE);
        const float2* p2  = (const float2*)(f2 + (size_t)gid * EE);
        const float2* p3  = (const float2*)(f3 + (size_t)gid * EE);

        float2 vr = rp[lane], va1 = a1p[lane], va2 = a2p[lane];
        float2 v1 = p1[lane], v2 = p2[lane], v3 = p3[lane];

        float dx, dy;
        dx = vr.x - v1.x;  dy = vr.y - v1.y;  float dr  = dx*dx + dy*dy;
        dx = va1.x - v2.x; dy = va1.y - v2.y; float da1 = dx*dx + dy*dy;
        dx = va2.x - v3.x; dy = va2.y - v3.y; float da2 = dx*dx + dy*dy;
        float s2 = v2.x*v2.x + v2.y*v2.y;
        float s3 = v3.x*v3.x + v3.y*v3.y;

        // tiled store of -2*fact (exact pow2 scaling in bf16)
        // lane covers k = {2*lane, 2*lane+1}; kslot = lane>>2
        size_t base = ((size_t)b << 19) + (size_t)(f >> 4) * 4096 +
                      ((size_t)(lane >> 2) << 8) + ((f & 15) << 4) + ((lane & 3) << 2);
        uint32_t pk2 = (uint32_t)f2bf(-2.f * v2.x) | ((uint32_t)f2bf(-2.f * v2.y) << 16);
        uint32_t pk3 = (uint32_t)f2bf(-2.f * v3.x) | ((uint32_t)f2bf(-2.f * v3.y) << 16);
        *(uint32_t*)(f2t + base) = pk2;
        *(uint32_t*)(f3t + base) = pk3;

        dr = wred_sum(dr); da1 = wred_sum(da1); da2 = wred_sum(da2);
        s2 = wred_sum(s2); s3 = wred_sum(s3);

        if (lane == 0) {
            bool fv = f < nbf[b];
            Csp[gid] = fv ? (dr + da1 + s3) : 1e30f;
            Cpo[gid] = fv ? (dr + da2 + s2) : 1e30f;
        }
    } else {
        int gid = (blockIdx.x - NFB) * 4 + (threadIdx.x >> 6);   // over B*N
        int b = gid >> 12;
        int n = gid & (NN - 1);
        const float2* p = (const float2*)(ent + (size_t)gid * EE);
        float2 v = p[lane];
        size_t base = ((size_t)b << 20) + (size_t)(n >> 4) * 4096 +
                      ((size_t)(lane >> 2) << 8) + ((n & 15) << 4) + ((lane & 3) << 2);
        *(uint32_t*)(entt + base) =
            (uint32_t)f2bf(v.x) | ((uint32_t)f2bf(v.y) << 16);
        float nrm = wred_sum(v.x*v.x + v.y*v.y);
        if (lane == 0) enorm[gid] = nrm;
    }
}

// ---------------------------------------------------------------------------
// Main fused GEMM-min kernel. NO LDS, NO barriers.
// 4096 independent single-wave blocks: bid = b(3 bits, XCD affinity) |
// ng(64-row group) | fs(3 bits). Each wave: 64 entity rows x 256 facts x both
// tensors = 16 tiles. Grid supplies 16 waves/CU = 4 waves/SIMD; VGPR=128
// (launch_bounds(64,2) — NOT (64,4): that forced VGPR=64 and spilled 1.5GB
// of scratch to HBM, R5 post-mortem) permits all 4. B-frags stream from
// XCD-local L2 as wave-contiguous 1KB loads in MFMA layout; 2-deep register
// pipeline. Facts pre-scaled by -2, acc initialized from C via MFMA C-in,
// so the epilogue is min-only. Writes partial mins to pm.
// ---------------------------------------------------------------------------
__global__ __launch_bounds__(64, 2) void kb_main(
    const char* __restrict__ entt, const char* __restrict__ f3t,
    const char* __restrict__ f2t,
    const float* __restrict__ Csp, const float* __restrict__ Cpo,
    float* __restrict__ pm)
{
    int bid = blockIdx.x;
    int b  = bid & 7;
    int r  = bid >> 3;          // 0..511
    int fs = r >> 6;            // 0..7
    int ng = r & 63;            // 64-row entity group
    int lane = threadIdx.x & 63;
    int l15 = lane & 15, kgrp = lane >> 4;

    // A-frags: 64 entity rows (4 ntiles) x full K from tiled entt
    short8 a[4][4];
    {
        const char* ab = entt + ((size_t)b << 20) + ((size_t)ng << 14) + (l15 << 4);
#pragma unroll
        for (int i = 0; i < 4; ++i)
#pragma unroll
            for (int kk = 0; kk < 4; ++kk)
                a[i][kk] = *(const short8*)(ab + i * 4096 + ((kk * 4 + kgrp) << 8));
    }

    const char* p3 = f3t + ((size_t)b << 19) + (size_t)fs * (16 * 4096) +
                     (kgrp << 8) + (l15 << 4);
    const char* p2 = f2t + ((size_t)b << 19) + (size_t)fs * (16 * 4096) +
                     (kgrp << 8) + (l15 << 4);
    const float* c3 = Csp + b * FF + fs * 256 + l15;
    const float* c2 = Cpo + b * FF + fs * 256 + l15;

    float rm3[4][4], rm2[4][4];
#pragma unroll
    for (int i = 0; i < 4; ++i)
#pragma unroll
        for (int q = 0; q < 4; ++q) { rm3[i][q] = 3.0e38f; rm2[i][q] = 3.0e38f; }

    short8 bA3[4], bA2[4], bB3[4], bB2[4];

#define LOADB(d3, d2, ft) do {                                              \
    _Pragma("unroll") for (int kk = 0; kk < 4; ++kk) {                      \
        d3[kk] = *(const short8*)(p3 + (ft) * 4096 + kk * 1024);            \
        d2[kk] = *(const short8*)(p2 + (ft) * 4096 + kk * 1024);            \
    } } while (0)

#define STEP(s3v, s2v, ft) do {                                             \
    float cv3 = c3[(ft) * 16], cv2 = c2[(ft) * 16];                         \
    floatx4 acc3[4], acc2[4];                                               \
    _Pragma("unroll") for (int i = 0; i < 4; ++i) {                         \
        acc3[i] = floatx4{cv3, cv3, cv3, cv3};                              \
        acc2[i] = floatx4{cv2, cv2, cv2, cv2};                              \
    }                                                                       \
    _Pragma("unroll") for (int kk = 0; kk < 4; ++kk)                        \
        _Pragma("unroll") for (int i = 0; i < 4; ++i)                       \
            acc3[i] = __builtin_amdgcn_mfma_f32_16x16x32_bf16(              \
                a[i][kk], s3v[kk], acc3[i], 0, 0, 0);                       \
    _Pragma("unroll") for (int kk = 0; kk < 4; ++kk)                        \
        _Pragma("unroll") for (int i = 0; i < 4; ++i)                       \
            acc2[i] = __builtin_amdgcn_mfma_f32_16x16x32_bf16(              \
                a[i][kk], s2v[kk], acc2[i], 0, 0, 0);                       \
    _Pragma("unroll") for (int i = 0; i < 4; ++i)                           \
        _Pragma("unroll") for (int q = 0; q < 4; ++q) {                     \
            rm3[i][q] = fminf(rm3[i][q], acc3[i][q]);                       \
            rm2[i][q] = fminf(rm2[i][q], acc2[i][q]);                       \
        } } while (0)

    LOADB(bA3, bA2, 0);
    for (int ft = 0; ft < 16; ft += 2) {
        LOADB(bB3, bB2, ft + 1);            // prefetch odd tile
        STEP(bA3, bA2, ft);
        if (ft < 14) LOADB(bA3, bA2, ft + 2);   // prefetch next even tile
        STEP(bB3, bB2, ft + 1);
    }
#undef LOADB
#undef STEP

    // lane-group min-reduce, write partial min-distances
    float* q0 = pm + (((size_t)fs * 2 + 0) * BB + b) * NN + ng * 64;
    float* q1 = pm + (((size_t)fs * 2 + 1) * BB + b) * NN + ng * 64;
#pragma unroll
    for (int i = 0; i < 4; ++i)
#pragma unroll
        for (int q = 0; q < 4; ++q) {
            float vs = rm3[i][q], vp = rm2[i][q];
#pragma unroll
            for (int o = 1; o < 16; o <<= 1) {
                vs = fminf(vs, __shfl_xor(vs, o, 64));
                vp = fminf(vp, __shfl_xor(vp, o, 64));
            }
            if (l15 == 0) {
                int row = i * 16 + kgrp * 4 + q;
                q0[row] = vs;
                q1[row] = vp;
            }
        }
}

// ---------------------------------------------------------------------------
// Combine: min over the 8 F-split partials, add ||ent||^2, exp, entity mask.
// ---------------------------------------------------------------------------
__global__ __launch_bounds__(512) void combine(
    const float* __restrict__ pm, const float* __restrict__ enorm,
    const int* __restrict__ nbe, float* __restrict__ out)
{
    int idx = blockIdx.x * 512 + threadIdx.x;   // over 2*B*N
    int br  = idx >> 15;
    int rem = idx & 32767;
    int b   = rem >> 12;
    int n   = rem & 4095;
    float d = 3.0e38f;
#pragma unroll
    for (int fsp = 0; fsp < 8; ++fsp)
        d = fminf(d, pm[(((size_t)fsp * 2 + br) * BB + b) * NN + n]);
    bool valid = n < nbe[b];
    out[idx] = valid ? __expf(-0.5f * (d + enorm[(size_t)b * NN + n])) : 0.f;
}

// ---------------------------------------------------------------------------
// Workspace layout (bytes):
//   [0,      4MB)   fact2 bf16 * -2, MFMA-tiled
//   [4MB,    8MB)   fact3 bf16 * -2, MFMA-tiled
//   [8MB,   16MB)   ent bf16, MFMA-tiled
//   [16MB,        +64KB)   C_sp
//   [16MB+64K,    +64KB)   C_po
//   [16MB+128K,  +128KB)   ent_norm
//   [16MB+256K,    +2MB)   pm partial mins [fs*2+branch][B][N]
// ---------------------------------------------------------------------------
extern "C" void kernel_launch(void* const* d_in, const int* in_sizes, int n_in,
                              void* d_out, int out_size, void* d_ws, size_t ws_size,
                              hipStream_t stream) {
    const float* rel  = (const float*)d_in[0];
    const float* arg1 = (const float*)d_in[1];
    const float* arg2 = (const float*)d_in[2];
    const float* f1   = (const float*)d_in[3];
    const float* f2   = (const float*)d_in[4];
    const float* f3   = (const float*)d_in[5];
    const float* ent  = (const float*)d_in[6];
    const int*   nbf  = (const int*)d_in[7];
    const int*   nbe  = (const int*)d_in[8];

    char* ws = (char*)d_ws;
    char* f2t  = ws;
    char* f3t  = ws + (4u << 20);
    char* entt = ws + (8u << 20);
    float* Csp   = (float*)(ws + (16u << 20));
    float* Cpo   = (float*)(ws + (16u << 20) + 65536);
    float* enorm = (float*)(ws + (16u << 20) + 131072);
    float* pm    = (float*)(ws + (16u << 20) + 262144);
    float* out = (float*)d_out;

    hipLaunchKernelGGL(prep_all, dim3(NFB + NEB), dim3(256), 0, stream,
                       rel, arg1, arg2, f1, f2, f3, ent, nbf,
                       f2t, f3t, entt, Csp, Cpo, enorm);
    hipLaunchKernelGGL(kb_main, dim3(4096), dim3(64), 0, stream,
                       entt, f3t, f2t, Csp, Cpo, pm);
    hipLaunchKernelGGL(combine, dim3(128), dim3(512), 0, stream,
                       pm, enorm, nbe, out);
}